// Round 9
// baseline (280.247 us; speedup 1.0000x reference)
//
#include <hip/hip_runtime.h>

#define N 4096
#define CORE_W 116        // core columns per strip
#define NSTRIP 36         // 36*116 = 4176 >= 4096
#define ROWS 26           // output rows per wave
#define NCHUNK 158        // 158*26 = 4108 >= 4096
#define STEPS 36          // ROWS + 10; multiple of 12 -> no per-step guards
#define NSLOT 32          // atomic spreading slots
#define WPB 4             // independent waves per 256-thread block

// R6 pipeline (skew-1, 2 cols/lane, 128-wide strips) with BATCHED LOADS:
// pred/gt rolling register FIFOs deepened to 12 rows; all 12 loads for a
// 6-step group are issued together at group top, so consumption waits are
// vmcnt(high) with ~2 compute-steps of slack instead of a per-step
// near-vmcnt(0) stall. Slot invariant: slot_D(row r) = (r - t0) mod D,
// compile-time via 12x unroll. Correctness cascade: correct_j(r) for
// r >= t0 + j with t0 = R0-5 (stage j at step t handles row t-j); first
// real gt row t0+1 = R0-4 is exactly what correct5(R0) needs. Rows beyond
// R1 / warm-up rows are finite garbage discarded by row guards; padded
// rows (r<0, r>=N, edge cols) have g=0 -> stay exactly 0. No LDS barriers.

typedef float2 f2;
__device__ __forceinline__ f2 mkf2(float a, float b){ f2 r; r.x=a; r.y=b; return r; }

__device__ __forceinline__ f2 hsum(f2 v) {
    float m = v.x + v.y;
    float L = __shfl_up(v.y, 1);     // lane l-1's right col
    float R = __shfl_down(v.x, 1);   // lane l+1's left col
    return mkf2(L + m, m + R);
}

__device__ __forceinline__ f2 add3(f2 a, f2 b, f2 c) {
    return mkf2(a.x + b.x + c.x, a.y + b.y + c.y);
}

__device__ __forceinline__ f2 stepf(f2 p, f2 d, f2 g, f2* fn) {
    const float C1 = 28.853900817779268f;   // 20*log2(e)
    const float C2 = 14.426950408889634f;   // 10*log2(e)
    f2 o, f;
    {
        float dd = fminf(fmaxf(d.x, 0.f), 1.f);
        float u  = __builtin_fmaf(p.x - dd, C1, C2);
        float sh = __builtin_amdgcn_rcpf(1.f + __builtin_amdgcn_exp2f(u));
        f.x = g.x * sh; o.x = p.x + f.x;
    }
    {
        float dd = fminf(fmaxf(d.y, 0.f), 1.f);
        float u  = __builtin_fmaf(p.y - dd, C1, C2);
        float sh = __builtin_amdgcn_rcpf(1.f + __builtin_amdgcn_exp2f(u));
        f.y = g.y * sh; o.y = p.y + f.y;
    }
    *fn = f;
    return o;
}

__device__ __forceinline__ f2 ldrow(const float* __restrict__ base, int row,
                                    int gc, bool edge) {
    if (row < 0 || row >= N) return mkf2(0.f, 0.f);
    if (!edge) return *(const f2*)(base + (size_t)row * N + gc);  // gc even -> aligned
    float a = 0.f, b = 0.f;
    if (gc >= 0 && gc < N)         a = base[(size_t)row * N + gc];
    if (gc + 1 >= 0 && gc + 1 < N) b = base[(size_t)row * N + gc + 1];
    return mkf2(a, b);
}

__global__ __launch_bounds__(64 * WPB) void wlc_main(
    const float* __restrict__ pred,
    const float* __restrict__ gt,
    float* __restrict__ ws)
{
    const int tid  = threadIdx.x;
    const int lane = tid & 63;
    const int wid  = blockIdx.x * WPB + (tid >> 6);   // global wave id
    const int strip = wid % NSTRIP;
    const int chunk = wid / NSTRIP;

    const int x0 = strip * CORE_W - 6;
    const int gc = x0 + 2 * lane;
    const bool edge = (strip == 0) || (strip == NSTRIP - 1);

    const int R0 = chunk * ROWS;
    const int R1 = min(R0 + ROWS, N);
    const int t0 = R0 - 5;           // warm-up: correct5(r) for r >= t0+5 = R0

    // column accumulation masks: core cols -> lanes 3..60
    const float colm = (lane >= 3 && lane <= 60) ? 1.f : 0.f;
    const float m0 = (gc     < N) ? colm : 0.f;
    const float m1 = (gc + 1 < N) ? colm : 0.f;

    // rolling register state (zero-init -> finite warm-up garbage)
    f2 pr[12], gb[12];
    f2 h0[3], h1[3], h2[3], h3[3], h4[3];
    f2 o1[2], o2[2], o3[2], o4[2];
#pragma unroll
    for (int i = 0; i < 12; ++i) { pr[i] = mkf2(0,0); gb[i] = mkf2(0,0); }
#pragma unroll
    for (int i = 0; i < 3; ++i) { h0[i]=h1[i]=h2[i]=h3[i]=h4[i]=mkf2(0,0); }
#pragma unroll
    for (int i = 0; i < 2; ++i) { o1[i]=o2[i]=o3[i]=o4[i]=mkf2(0,0); }

    // prologue: slot(r) = (r - t0) mod 12; pred rows t0, t0+1 -> slots 0,1.
    // gt rows <= t0 are provably uninfluential -> stay zero.
    pr[0] = ldrow(pred, t0,     gc, edge);
    pr[1] = ldrow(pred, t0 + 1, gc, edge);

    float s1a=0.f, s2a=0.f, s3a=0.f, s4a=0.f, s5a=0.f, gsa=0.f;

    // compile-time slot macros for row t+o at t = tb + k (k in [0,12))
#define S12(o) ((k + (o) + 12) % 12)
#define S3(o)  ((k + (o) + 12) % 3)
#define S2(o)  ((k + (o) + 12) % 2)

    for (int tb = t0; tb < t0 + STEPS; tb += 12) {
#pragma unroll
        for (int half = 0; half < 2; ++half) {
            const int k0  = 6 * half;
            const int tau = tb + k0;

            // ---- batched loads for steps tau..tau+5 (consumption-ordered
            //      interleave; first use ~2 compute-steps after issue) ----
#pragma unroll
            for (int j = 0; j < 6; ++j) {
                if (tau + 2 + j <= R1 + 4)
                    pr[(k0 + 2 + j) % 12] = ldrow(pred, tau + 2 + j, gc, edge);
                if (tau + 1 + j <= R1 + 3)
                    gb[(k0 + 1 + j) % 12] = ldrow(gt,   tau + 1 + j, gc, edge);
            }

            // ---- 6 compute steps, no loads, no step guards ----
#pragma unroll
            for (int kk = 0; kk < 6; ++kk) {
                const int k = k0 + kk;
                const int t = tb + k;

                // ingest: h-sum of input row t
                h0[S3(0)] = hsum(pr[S12(0)]);

                f2 d, fn, o;
                // stage 1: row t-1 (p straight from pred)
                d = add3(h0[0], h0[1], h0[2]);   // rows t-2..t
                o = stepf(pr[S12(-1)], d, gb[S12(-1)], &fn);
                { int r = t - 1; if (r >= R0 && r < R1) s1a += fn.x*m0 + fn.y*m1; }
                h1[S3(-1)] = hsum(o);  o1[S2(-1)] = o;

                // stage 2: row t-2
                d = add3(h1[0], h1[1], h1[2]);   // rows t-3..t-1
                o = stepf(o1[S2(-2)], d, gb[S12(-2)], &fn);
                { int r = t - 2; if (r >= R0 && r < R1) s2a += fn.x*m0 + fn.y*m1; }
                h2[S3(-2)] = hsum(o);  o2[S2(-2)] = o;

                // stage 3: row t-3
                d = add3(h2[0], h2[1], h2[2]);   // rows t-4..t-2
                o = stepf(o2[S2(-3)], d, gb[S12(-3)], &fn);
                { int r = t - 3; if (r >= R0 && r < R1) s3a += fn.x*m0 + fn.y*m1; }
                h3[S3(-3)] = hsum(o);  o3[S2(-3)] = o;

                // stage 4: row t-4
                d = add3(h3[0], h3[1], h3[2]);   // rows t-5..t-3
                o = stepf(o3[S2(-4)], d, gb[S12(-4)], &fn);
                { int r = t - 4; if (r >= R0 && r < R1) s4a += fn.x*m0 + fn.y*m1; }
                h4[S3(-4)] = hsum(o);  o4[S2(-4)] = o;

                // stage 5: row t-5 (output not fed forward)
                {
                    const f2 g5 = gb[S12(-5)];
                    d = add3(h4[0], h4[1], h4[2]);   // rows t-6..t-4
                    o = stepf(o4[S2(-5)], d, g5, &fn);
                    int r = t - 5;
                    if (r >= R0 && r < R1) {
                        s5a += fn.x*m0 + fn.y*m1;
                        gsa += g5.x*m0 + g5.y*m1;
                    }
                }
            }
        }
    }
#undef S12
#undef S3
#undef S2

    // per-wave reduction -> 6 atomics, spread over NSLOT slot copies
    float vals[6] = {gsa, s1a, s2a, s3a, s4a, s5a};
    const int slot = wid & (NSLOT - 1);
#pragma unroll
    for (int kk = 0; kk < 6; ++kk) {
        float v = vals[kk];
#pragma unroll
        for (int off = 32; off > 0; off >>= 1)
            v += __shfl_down(v, off, 64);
        if (lane == 0) atomicAdd(&ws[slot * 32 + kk], v);
    }
}

__global__ void wlc_final(const float* __restrict__ ws, float* __restrict__ out)
{
    float t[6] = {0.f, 0.f, 0.f, 0.f, 0.f, 0.f};
    for (int s = 0; s < NSLOT; ++s)
#pragma unroll
        for (int kk = 0; kk < 6; ++kk)
            t[kk] += ws[s * 32 + kk];
    out[0] = (1.f * t[1] + 4.f * t[2] + 9.f * t[3] + 16.f * t[4] + 25.f * t[5]) / t[0];
}

extern "C" void kernel_launch(void* const* d_in, const int* in_sizes, int n_in,
                              void* d_out, int out_size, void* d_ws, size_t ws_size,
                              hipStream_t stream)
{
    const float* pred = (const float*)d_in[0];
    const float* gtp  = (const float*)d_in[1];
    float* ws = (float*)d_ws;

    hipMemsetAsync(d_ws, 0, NSLOT * 32 * sizeof(float), stream);

    // NSTRIP*NCHUNK = 5688 waves = 1422 blocks of 4 independent waves
    wlc_main<<<dim3((NSTRIP * NCHUNK) / WPB), 64 * WPB, 0, stream>>>(pred, gtp, ws);
    wlc_final<<<1, 1, 0, stream>>>(ws, (float*)d_out);
}